// Round 2
// baseline (299.629 us; speedup 1.0000x reference)
//
#include <hip/hip_runtime.h>

typedef unsigned short u16;
typedef unsigned int u32;
typedef unsigned long long u64;
typedef __attribute__((ext_vector_type(8))) short short8;
typedef __attribute__((ext_vector_type(4))) float f32x4;

#define QSCALE 0.18033688f   /* 0.125 * log2(e), folded into Q at projection */

// ---------- helpers ----------
__device__ __forceinline__ u16 f2bf(float f) {
  u32 u = __builtin_bit_cast(u32, f);
  u += 0x7fffu + ((u >> 16) & 1u);   // RNE
  return (u16)(u >> 16);
}

__device__ __forceinline__ float fexp2(float x) {
#if __has_builtin(__builtin_amdgcn_exp2f)
  return __builtin_amdgcn_exp2f(x);   // v_exp_f32
#else
  return exp2f(x);
#endif
}

// async global->LDS, 16B per lane. LDS dest is wave-uniform base + lane*16.
__device__ __forceinline__ void glds16(u16* lds, const u16* g) {
  __builtin_amdgcn_global_load_lds(
      (const __attribute__((address_space(1))) u32*)g,
      (__attribute__((address_space(3))) u32*)lds, 16, 0, 0);
}

#define MFMA(a, b, c) __builtin_amdgcn_mfma_f32_16x16x32_bf16((a), (b), (c), 0, 0, 0)

// LDS tile layout (XOR-swizzled), tile = [64 rows][64 u16 cols] = 8 KiB:
//   physical 16B-chunk slot p of row r holds logical col-chunk (p ^ (r&7)).
// b128 reads hit 8 distinct 16B regions per half-wave (4-way = b128 minimum).
//
// XCD swizzle (R10): blocks sharing the LARGE operand strip are spaced a
// multiple of 8 apart in dispatch order -> same XCD L2. Per-XCD working set:
// strips + weights ~ 4MB = L2 size. (R7 verified bid%8->XCD on this HW.)

// ---------- kernel 1: fused prep (x cvt | W transposes | mask scan) ----------
__global__ __launch_bounds__(256) void prep(const float* __restrict__ x,
                                            const int* __restrict__ mask,
                                            const float* __restrict__ Wqkv,
                                            const float* __restrict__ Wproj,
                                            u16* __restrict__ xb,
                                            u16* __restrict__ wqkvt,
                                            u16* __restrict__ wprojt,
                                            int* __restrict__ s2t,
                                            int* __restrict__ nkbuf) {
  __shared__ float tile[64][65];
  __shared__ int wtot[4];
  __shared__ int wbase[5];
  const int bid = blockIdx.x, t = threadIdx.x;

  if (bid < 8192) {                    // ---- role: x fp32 -> bf16 ----
    int i = bid * 256 + t;
    float4 v = ((const float4*)x)[i];
    union { u16 s[4]; u64 ll; } u;
    u.s[0] = f2bf(v.x); u.s[1] = f2bf(v.y); u.s[2] = f2bf(v.z); u.s[3] = f2bf(v.w);
    ((u64*)xb)[i] = u.ll;
    return;
  }
  if (bid < 9216) {                    // ---- role: W transpose+cvt ----
    const float* Wm; u16* Wt; int Cc, bj, bi;
    if (bid < 8960) { int tt = bid - 8192; Wm = Wqkv;  Wt = wqkvt;  Cc = 3072; bj = tt % 48; bi = tt / 48; }
    else            { int tt = bid - 8960; Wm = Wproj; Wt = wprojt; Cc = 1024; bj = tt & 15; bi = tt >> 4; }
    const int r = t >> 4, c4 = (t & 15) << 2;
    for (int rr = r; rr < 64; rr += 16) {
      float4 v = *(const float4*)&Wm[(size_t)(bi * 64 + rr) * Cc + bj * 64 + c4];
      tile[rr][c4] = v.x; tile[rr][c4 + 1] = v.y; tile[rr][c4 + 2] = v.z; tile[rr][c4 + 3] = v.w;
    }
    __syncthreads();
    for (int rr = r; rr < 64; rr += 16) {
      union { u16 s[4]; u64 ll; } u;
      u.s[0] = f2bf(tile[c4][rr]);
      u.s[1] = f2bf(tile[c4 + 1][rr]);
      u.s[2] = f2bf(tile[c4 + 2][rr]);
      u.s[3] = f2bf(tile[c4 + 3][rr]);
      *(u64*)&Wt[(size_t)(bj * 64 + rr) * 1024 + bi * 64 + c4] = u.ll;
    }
    return;
  }
  // ---- role: per-batch stable partition of key tokens ----
  const int b = bid - 9216;
  const int lane = t & 63, w = t >> 6;
  int m8[8], c = 0;
  #pragma unroll
  for (int j = 0; j < 8; j++) {
    m8[j] = (mask[b * 2048 + t * 8 + j] == 1);
    c += m8[j];
  }
  int incl = c;
  #pragma unroll
  for (int off = 1; off < 64; off <<= 1) {
    int v = __shfl_up(incl, off);
    if (lane >= off) incl += v;
  }
  if (lane == 63) wtot[w] = incl;
  __syncthreads();
  if (t == 0) {
    int s = 0;
    for (int i = 0; i < 4; i++) { wbase[i] = s; s += wtot[i]; }
    wbase[4] = s;
  }
  __syncthreads();
  const int nk = wbase[4];
  int urun = wbase[w] + incl - c;
  #pragma unroll
  for (int j = 0; j < 8; j++) {
    int tok = t * 8 + j;
    int slot = m8[j] ? urun : nk + (tok - urun);
    s2t[b * 2048 + slot] = b * 2048 + tok;
    urun += m8[j];
  }
  if (t == 0) nkbuf[b] = nk;
}

// ---------- kernel 2: fused Q/K/V GEMM, XCD-swizzled, compacted K/V ----------
// Q role: m0=(sub&63)*128 (x-strip), n0=(sub>>6)*128 — same-strip blocks 64
// apart -> same XCD. K/V roles: slot-strips remapped so likely-DEAD strips
// (slot >= 1024; nk ~ Binom(2048,.5) ~ 1024) dispatch LAST within the role —
// with 5 blocks/CU residency the first-resident waves are then ~all live,
// trimming the makespan tail. Same-strip spacing 32 (%8==0) keeps XCD-L2.
// Q-role epilogue pre-multiplies by QSCALE so attention's exp is bare exp2(s).
// __launch_bounds__(256,5): 5 waves/EU -> 5 blocks/CU; LDS 5*32KiB = 160KiB
// exactly; VGPR=64 well under the 102 cap -> no spill risk.
__global__ __launch_bounds__(256, 5) void gemm_fused(const u16* __restrict__ xb,
                                                     const u16* __restrict__ wqkvt,
                                                     const int* __restrict__ s2t,
                                                     const int* __restrict__ nkbuf,
                                                     u16* __restrict__ qbuf,
                                                     u16* __restrict__ kc,
                                                     u16* __restrict__ vtc) {
  __shared__ u16 Asm[128 * 64];
  __shared__ u16 Bsm[128 * 64];
  const int bid = blockIdx.x;
  const int role = bid >> 9;            // 0=Q 1=K 2=V
  const int sub = bid & 511;
  const int tid = threadIdx.x, lane = tid & 63, w = tid >> 6;
  const int quad = lane >> 4, l15 = lane & 15;
  const int wm = (w >> 1) * 64, wn = (w & 1) * 64;
  const int srow = lane >> 3;
  const int gcc = ((lane & 7) ^ srow) * 8;
  const int rx8 = (l15 & 7);

  int m0, n0;
  if (role == 0) {
    m0 = (sub & 63) * 128; n0 = (sub >> 6) * 128;
  } else {
    // dead-likely slot strips (st>=8 within batch) go last: q=sub>>8 selects
    // high half-strips; strip = batch*16 + (m5&7) + q*8, bijective over 0..63.
    int q = sub >> 8, r = sub & 255;
    int e = r >> 5, m5 = r & 31;
    int strip = ((m5 >> 3) << 4) + (m5 & 7) + (q << 3);
    if (role == 1) { m0 = strip * 128; n0 = e * 128; }
    else           { m0 = e * 128; n0 = strip * 128; }
  }
  if (role == 1 && (m0 & 2047) >= nkbuf[m0 >> 11]) return;
  if (role == 2 && (n0 & 2047) >= nkbuf[n0 >> 11]) return;

  // per-lane source row ids for the 4 staged chunks
  int arow[4], brow[4];
  #pragma unroll
  for (int c = 0; c < 4; ++c) {
    int rit = (w * 4 + c) * 8 + srow;   // row within the 128-tile
    if (role == 0)      { arow[c] = m0 + rit;            brow[c] = n0 + rit; }
    else if (role == 1) { arow[c] = s2t[m0 + rit];       brow[c] = 1024 + n0 + rit; }
    else                { arow[c] = 2048 + m0 + rit;     brow[c] = s2t[n0 + rit]; }
  }
  const u16 *Asrc = (role == 2) ? wqkvt : xb;
  const u16 *Bsrc = (role == 2) ? xb : wqkvt;

  f32x4 acc[4][4];
  #pragma unroll
  for (int i = 0; i < 4; i++)
    #pragma unroll
    for (int j = 0; j < 4; j++)
      #pragma unroll
      for (int r = 0; r < 4; r++) acc[i][j][r] = 0.f;

  for (int kt = 0; kt < 1024; kt += 64) {
    __syncthreads();
    #pragma unroll
    for (int c = 0; c < 4; ++c) {
      int chunk = w * 4 + c;
      glds16(&Asm[chunk * 512], &Asrc[(size_t)arow[c] * 1024 + kt + gcc]);
      glds16(&Bsm[chunk * 512], &Bsrc[(size_t)brow[c] * 1024 + kt + gcc]);
    }
    __syncthreads();
    #pragma unroll
    for (int ks = 0; ks < 2; ++ks) {
      int pc = ((ks * 4 + quad) ^ rx8) * 8;
      short8 av[4], bv[4];
      #pragma unroll
      for (int i = 0; i < 4; i++)
        av[i] = *(const short8*)&Asm[(wm + i * 16 + l15) * 64 + pc];
      #pragma unroll
      for (int j = 0; j < 4; j++)
        bv[j] = *(const short8*)&Bsm[(wn + j * 16 + l15) * 64 + pc];
      #pragma unroll
      for (int i = 0; i < 4; i++)
        #pragma unroll
        for (int j = 0; j < 4; j++)
          acc[i][j] = MFMA(av[i], bv[j], acc[i][j]);
    }
  }

  if (role == 2) {
    #pragma unroll
    for (int j = 0; j < 4; j++) {
      int col = n0 + wn + j * 16 + l15;           // global slot 0..8191
      int bb = col >> 11, sl = col & 2047;
      #pragma unroll
      for (int i = 0; i < 4; i++)
        #pragma unroll
        for (int r = 0; r < 4; r++) {
          int row = m0 + wm + i * 16 + quad * 4 + r;   // d in 0..1023
          vtc[(size_t)(bb * 1024 + row) * 2048 + sl] = f2bf(acc[i][j][r]);
        }
    }
  } else {
    u16* dst = (role == 0) ? qbuf : kc;
    const float sc = (role == 0) ? QSCALE : 1.f;
    #pragma unroll
    for (int i = 0; i < 4; i++)
      #pragma unroll
      for (int j = 0; j < 4; j++) {
        int col = n0 + wn + j * 16 + l15;
        #pragma unroll
        for (int r = 0; r < 4; r++) {
          int row = m0 + wm + i * 16 + quad * 4 + r;
          dst[(size_t)row * 1024 + col] = f2bf(acc[i][j][r] * sc);
        }
      }
  }
}

// ---------- kernel 3: flash attention, register P, BK=128, MFMA row-sums ----------
// T5: s_setprio(1) around MFMA clusters — attn blocks are independent (2/CU,
// no inter-block lockstep) so scheduler arbitration pays here (m191: +4-7%);
// NOT applied to the lockstep GEMMs (m190: hurts).
__global__ __launch_bounds__(256, 2) void attn_kernel(const u16* __restrict__ q,
                                                      const u16* __restrict__ kc,
                                                      const u16* __restrict__ vtc,
                                                      const int* __restrict__ nkbuf,
                                                      u16* __restrict__ ao) {
  __shared__ u16 Ksm[2][64 * 64];       // π-permuted key rows, swizzled cols (d)
  __shared__ u16 Vsm[2][64 * 64];       // [d][k_local] linear keys, swizzled
  const int h = blockIdx.x, b = blockIdx.y, qt = blockIdx.z;
  const int tid = threadIdx.x, lane = tid & 63, w = tid >> 6;
  const int quad = lane >> 4, l15 = lane & 15;
  const int q0 = qt * 256 + w * 64;     // wave's q base within batch
  const int srow = lane >> 3;
  const int gcc = ((lane & 7) ^ srow) * 8;
  const int rx8 = (l15 & 7);
  const int nk = nkbuf[b];
  const int nt2 = (nk + 127) >> 7;
  const int quad8 = quad * 8;

  // staging rows + π for K source
  int vrow[2], prow[2];
  #pragma unroll
  for (int c = 0; c < 2; ++c) {
    int row = (w * 2 + c) * 8 + srow;
    vrow[c] = row;
    prow[c] = ((row >> 4) & 1) * 32 + ((row >> 2) & 3) * 8 + ((row >> 5) & 1) * 4 + (row & 3);
  }

  // ones B-fragment (bf16 1.0 splat) for MFMA row-sums
  short8 ones;
  #pragma unroll
  for (int z = 0; z < 8; z++) ones[z] = (short)0x3F80;

  // Q fragments (B-operand): n=q=l15(+16i), k=d=quad*8+j (+32ks)
  short8 qf[4][2];
  #pragma unroll
  for (int i = 0; i < 4; i++)
    #pragma unroll
    for (int ks = 0; ks < 2; ks++)
      qf[i][ks] = *(const short8*)&q[(size_t)(b * 2048 + q0 + i * 16 + l15) * 1024 +
                                     h * 64 + ks * 32 + quad * 8];

  f32x4 o[4][4], osum[4];
  #pragma unroll
  for (int i = 0; i < 4; i++) {
    #pragma unroll
    for (int r = 0; r < 4; r++) osum[i][r] = 0.f;
    #pragma unroll
    for (int jd = 0; jd < 4; jd++)
      #pragma unroll
      for (int r = 0; r < 4; r++) o[i][jd][r] = 0.f;
  }

#define SUBTILE(st_, kbase_)                                                           \
  {                                                                                    \
    f32x4 s[4][4];                                                                     \
    _Pragma("unroll") for (int j = 0; j < 4; j++)                                      \
      _Pragma("unroll") for (int i = 0; i < 4; i++)                                    \
        _Pragma("unroll") for (int r = 0; r < 4; r++) s[j][i][r] = 0.f;                \
    _Pragma("unroll") for (int ks = 0; ks < 2; ks++) {                                 \
      int pc = ((ks * 4 + quad) ^ rx8) * 8;                                            \
      short8 kf[4];                                                                    \
      _Pragma("unroll") for (int j = 0; j < 4; j++)                                    \
        kf[j] = *(const short8*)&Ksm[st_][(j * 16 + l15) * 64 + pc];                   \
      __builtin_amdgcn_s_setprio(1);                                                   \
      _Pragma("unroll") for (int j = 0; j < 4; j++)                                    \
        _Pragma("unroll") for (int i = 0; i < 4; i++)                                  \
          s[j][i] = MFMA(kf[j], qf[i][ks], s[j][i]);                                   \
      __builtin_amdgcn_s_setprio(0);                                                   \
    }                                                                                  \
    const bool tail = ((kbase_) + 64 > nk);                                            \
    short8 pf[4][2];                                                                   \
    _Pragma("unroll") for (int i = 0; i < 4; i++) {                                    \
      float p[4][4];                                                                   \
      if (!tail) {                                                                     \
        _Pragma("unroll") for (int j = 0; j < 4; j++)                                  \
          _Pragma("unroll") for (int r = 0; r < 4; r++)                                \
            p[j][r] = fexp2(s[j][i][r]);                                               \
      } else {                                                                         \
        _Pragma("unroll") for (int j = 0; j < 4; j++)                                  \
          _Pragma("unroll") for (int r = 0; r < 4; r++) {                              \
            int slot = (kbase_) + (j & 1) * 32 + quad8 + (j >> 1) * 4 + r;             \
            float e = fexp2(s[j][i][r]);                                               \
            p[j][r] = (slot < nk) ? e : 0.f;                                           \
          }                                                                            \
      }                                                                                \
      _Pragma("unroll") for (int ks = 0; ks < 2; ks++) {                               \
        union { u32 u[4]; short8 v; } pk;                                              \
        u32 a0 = __builtin_bit_cast(u32, p[ks][0]) + 0x8000u;                          \
        u32 a1 = __builtin_bit_cast(u32, p[ks][1]) + 0x8000u;                          \
        u32 a2 = __builtin_bit_cast(u32, p[ks][2]) + 0x8000u;                          \
        u32 a3 = __builtin_bit_cast(u32, p[ks][3]) + 0x8000u;                          \
        u32 b0 = __builtin_bit_cast(u32, p[ks + 2][0]) + 0x8000u;                      \
        u32 b1 = __builtin_bit_cast(u32, p[ks + 2][1]) + 0x8000u;                      \
        u32 b2 = __builtin_bit_cast(u32, p[ks + 2][2]) + 0x8000u;                      \
        u32 b3 = __builtin_bit_cast(u32, p[ks + 2][3]) + 0x8000u;                      \
        pk.u[0] = __builtin_amdgcn_perm(a1, a0, 0x07060302u);                          \
        pk.u[1] = __builtin_amdgcn_perm(a3, a2, 0x07060302u);                          \
        pk.u[2] = __builtin_amdgcn_perm(b1, b0, 0x07060302u);                          \
        pk.u[3] = __builtin_amdgcn_perm(b3, b2, 0x07060302u);                          \
        pf[i][ks] = pk.v;                                                              \
      }                                                                                \
    }                                                                                  \
    _Pragma("unroll") for (int ks = 0; ks < 2; ks++) {                                 \
      int pcv = ((ks * 4 + quad) ^ rx8) * 8;                                           \
      short8 vf[4];                                                                    \
      _Pragma("unroll") for (int jd = 0; jd < 4; jd++)                                 \
        vf[jd] = *(const short8*)&Vsm[st_][(jd * 16 + l15) * 64 + pcv];                \
      __builtin_amdgcn_s_setprio(1);                                                   \
      _Pragma("unroll") for (int i = 0; i < 4; i++) {                                  \
        osum[i] = MFMA(pf[i][ks], ones, osum[i]);                                      \
        _Pragma("unroll") for (int jd = 0; jd < 4; jd++)                               \
          o[i][jd] = MFMA(pf[i][ks], vf[jd], o[i][jd]);                                \
      }                                                                                \
      __builtin_amdgcn_s_setprio(0);                                                   \
    }                                                                                  \
  }

  for (int t = 0; t < nt2; ++t) {
    const int k0 = t * 128;
    __syncthreads();
    #pragma unroll
    for (int c = 0; c < 2; ++c) {
      int chunk = w * 2 + c;
      glds16(&Ksm[0][chunk * 512],
             &kc[(size_t)(b * 2048 + k0 + prow[c]) * 1024 + h * 64 + gcc]);
      glds16(&Vsm[0][chunk * 512],
             &vtc[(size_t)(b * 1024 + h * 64 + vrow[c]) * 2048 + k0 + gcc]);
      glds16(&Ksm[1][chunk * 512],
             &kc[(size_t)(b * 2048 + k0 + 64 + prow[c]) * 1024 + h * 64 + gcc]);
      glds16(&Vsm[1][chunk * 512],
             &vtc[(size_t)(b * 1024 + h * 64 + vrow[c]) * 2048 + k0 + 64 + gcc]);
    }
    __syncthreads();

    SUBTILE(0, k0)
    if (k0 + 64 < nk) SUBTILE(1, k0 + 64)
  }
#undef SUBTILE

  // epilogue: osum rows == o rows (quad*4+r) — direct normalize, no shuffles
  #pragma unroll
  for (int i = 0; i < 4; i++)
    #pragma unroll
    for (int r = 0; r < 4; r++) {
      float inv = 1.f / osum[i][r];
      size_t row = (size_t)(b * 2048 + q0 + i * 16 + quad * 4 + r);
      #pragma unroll
      for (int jd = 0; jd < 4; jd++)
        ao[row * 1024 + h * 64 + jd * 16 + l15] = f2bf(o[i][jd][r] * inv);
    }
}

// ---------- kernel 4: output projection + bias (XCD-swizzled flat grid) ----------
// 512 blocks: m0=(bid&63)*128 (aobuf strip, 16MB operand), n0=(bid>>6)*128.
__global__ __launch_bounds__(256, 3) void gemm_proj(const u16* __restrict__ A,
                                                    const u16* __restrict__ Bt,
                                                    const float* __restrict__ bias,
                                                    float* __restrict__ out) {
  __shared__ u16 Asm[128 * 64];
  __shared__ u16 Bsm[128 * 64];
  const int tid = threadIdx.x, lane = tid & 63, w = tid >> 6;
  const int quad = lane >> 4, l15 = lane & 15;
  const int m0 = (blockIdx.x & 63) * 128, n0 = (blockIdx.x >> 6) * 128;
  const int wm = (w >> 1) * 64, wn = (w & 1) * 64;
  const int srow = lane >> 3;
  const int gcc = ((lane & 7) ^ srow) * 8;
  const int rx8 = (l15 & 7);
  f32x4 acc[4][4];
  #pragma unroll
  for (int i = 0; i < 4; i++)
    #pragma unroll
    for (int j = 0; j < 4; j++)
      #pragma unroll
      for (int r = 0; r < 4; r++) acc[i][j][r] = 0.f;

  for (int kt = 0; kt < 1024; kt += 64) {
    __syncthreads();
    #pragma unroll
    for (int c = 0; c < 4; ++c) {
      int chunk = w * 4 + c;
      int row = chunk * 8 + srow;
      glds16(&Asm[chunk * 512], &A[(size_t)(m0 + row) * 1024 + kt + gcc]);
      glds16(&Bsm[chunk * 512], &Bt[(size_t)(n0 + row) * 1024 + kt + gcc]);
    }
    __syncthreads();
    #pragma unroll
    for (int ks = 0; ks < 2; ++ks) {
      int pc = ((ks * 4 + quad) ^ rx8) * 8;
      short8 av[4], bv[4];
      #pragma unroll
      for (int i = 0; i < 4; i++)
        av[i] = *(const short8*)&Asm[(wm + i * 16 + l15) * 64 + pc];
      #pragma unroll
      for (int j = 0; j < 4; j++)
        bv[j] = *(const short8*)&Bsm[(wn + j * 16 + l15) * 64 + pc];
      #pragma unroll
      for (int i = 0; i < 4; i++)
        #pragma unroll
        for (int j = 0; j < 4; j++)
          acc[i][j] = MFMA(av[i], bv[j], acc[i][j]);
    }
  }

  #pragma unroll
  for (int j = 0; j < 4; j++) {
    int col = n0 + wn + j * 16 + l15;
    float bj = bias[col];
    #pragma unroll
    for (int i = 0; i < 4; i++) {
      #pragma unroll
      for (int r = 0; r < 4; r++) {
        int row = m0 + wm + i * 16 + quad * 4 + r;
        out[(size_t)row * 1024 + col] = acc[i][j][r] + bj;
      }
    }
  }
}

// ---------- launch ----------
extern "C" void kernel_launch(void* const* d_in, const int* in_sizes, int n_in,
                              void* d_out, int out_size, void* d_ws, size_t ws_size,
                              hipStream_t stream) {
  (void)in_sizes; (void)n_in; (void)out_size; (void)ws_size;
  const float* x     = (const float*)d_in[0];
  const int*   mask  = (const int*)d_in[1];
  const float* Wqkv  = (const float*)d_in[2];
  const float* Wproj = (const float*)d_in[3];
  const float* bproj = (const float*)d_in[4];
  float* out = (float*)d_out;
  char* ws = (char*)d_ws;

  size_t off = 0;
  u16* xb     = (u16*)(ws + off); off += 8192ull * 1024 * 2;   // x bf16; REUSED as aobuf
  u16* wqkvt  = (u16*)(ws + off); off += 3072ull * 1024 * 2;   // Wqkv^T bf16 [3072][1024]
  u16* wprojt = (u16*)(ws + off); off += 1024ull * 1024 * 2;   // Wproj^T bf16 [1024][1024]
  u16* qbuf   = (u16*)(ws + off); off += 8192ull * 1024 * 2;   // Q (pre-scaled) bf16
  u16* kcbuf  = (u16*)(ws + off); off += 4096ull * 2048 * 2;   // K compact [b][slot][1024]
  u16* vtcbuf = (u16*)(ws + off); off += 4096ull * 2048 * 2;   // V^T compact [b][d][slot]
  int* s2t    = (int*)(ws + off); off += 8192ull * 4;          // slot -> global token
  int* nkbuf  = (int*)(ws + off); off += 4 * 4;                // per-batch nk
  u16* aobuf  = xb;   // xb's last read is gemm_fused; attn writes ao after -> safe alias

  prep<<<9220, 256, 0, stream>>>(x, mask, Wqkv, Wproj, xb, wqkvt, wprojt, s2t, nkbuf);
  gemm_fused<<<1536, 256, 0, stream>>>(xb, wqkvt, s2t, nkbuf, qbuf, kcbuf, vtcbuf);
  attn_kernel<<<dim3(16, 4, 8), 256, 0, stream>>>(qbuf, kcbuf, vtcbuf, nkbuf, aobuf);
  gemm_proj<<<512, 256, 0, stream>>>(aobuf, wprojt, bproj, out);
}

// Round 3
// 208.458 us; speedup vs baseline: 1.4374x; 1.4374x over previous
//
#include <hip/hip_runtime.h>

typedef unsigned short u16;
typedef unsigned int u32;
typedef unsigned long long u64;
typedef __attribute__((ext_vector_type(8))) short short8;
typedef __attribute__((ext_vector_type(4))) float f32x4;

#define QSCALE 0.18033688f   /* 0.125 * log2(e), folded into Q at projection */

// ---------- helpers ----------
__device__ __forceinline__ u16 f2bf(float f) {
  u32 u = __builtin_bit_cast(u32, f);
  u += 0x7fffu + ((u >> 16) & 1u);   // RNE
  return (u16)(u >> 16);
}

__device__ __forceinline__ float fexp2(float x) {
#if __has_builtin(__builtin_amdgcn_exp2f)
  return __builtin_amdgcn_exp2f(x);   // v_exp_f32
#else
  return exp2f(x);
#endif
}

// async global->LDS, 16B per lane. LDS dest is wave-uniform base + lane*16.
__device__ __forceinline__ void glds16(u16* lds, const u16* g) {
  __builtin_amdgcn_global_load_lds(
      (const __attribute__((address_space(1))) u32*)g,
      (__attribute__((address_space(3))) u32*)lds, 16, 0, 0);
}

#define MFMA(a, b, c) __builtin_amdgcn_mfma_f32_16x16x32_bf16((a), (b), (c), 0, 0, 0)

// LDS tile layout (XOR-swizzled), tile = [64 rows][64 u16 cols] = 8 KiB:
//   physical 16B-chunk slot p of row r holds logical col-chunk (p ^ (r&7)).
// b128 reads hit 8 distinct 16B regions per half-wave (4-way = b128 minimum).
//
// XCD swizzle: blocks sharing the LARGE operand strip are spaced a multiple
// of 8 apart in dispatch order -> same XCD L2.
//
// R2 LESSON (journal): __launch_bounds__(256,5) forced VGPR 64->48 and spilled
// the accumulators to scratch (WRITE_SIZE 34MB->271MB, 51->146us). Residency
// was already 5 blocks/CU (LDS-limited); the 2nd arg only constrains regalloc.
// Keep (256,4).

// ---------- kernel 1: fused prep (x cvt | W transposes | mask scan) ----------
__global__ __launch_bounds__(256) void prep(const float* __restrict__ x,
                                            const int* __restrict__ mask,
                                            const float* __restrict__ Wqkv,
                                            const float* __restrict__ Wproj,
                                            u16* __restrict__ xb,
                                            u16* __restrict__ wqkvt,
                                            u16* __restrict__ wprojt,
                                            int* __restrict__ s2t,
                                            int* __restrict__ nkbuf) {
  __shared__ float tile[64][65];
  __shared__ int wtot[4];
  __shared__ int wbase[5];
  const int bid = blockIdx.x, t = threadIdx.x;

  if (bid < 8192) {                    // ---- role: x fp32 -> bf16 ----
    int i = bid * 256 + t;
    float4 v = ((const float4*)x)[i];
    union { u16 s[4]; u64 ll; } u;
    u.s[0] = f2bf(v.x); u.s[1] = f2bf(v.y); u.s[2] = f2bf(v.z); u.s[3] = f2bf(v.w);
    ((u64*)xb)[i] = u.ll;
    return;
  }
  if (bid < 9216) {                    // ---- role: W transpose+cvt ----
    const float* Wm; u16* Wt; int Cc, bj, bi;
    if (bid < 8960) { int tt = bid - 8192; Wm = Wqkv;  Wt = wqkvt;  Cc = 3072; bj = tt % 48; bi = tt / 48; }
    else            { int tt = bid - 8960; Wm = Wproj; Wt = wprojt; Cc = 1024; bj = tt & 15; bi = tt >> 4; }
    const int r = t >> 4, c4 = (t & 15) << 2;
    for (int rr = r; rr < 64; rr += 16) {
      float4 v = *(const float4*)&Wm[(size_t)(bi * 64 + rr) * Cc + bj * 64 + c4];
      tile[rr][c4] = v.x; tile[rr][c4 + 1] = v.y; tile[rr][c4 + 2] = v.z; tile[rr][c4 + 3] = v.w;
    }
    __syncthreads();
    for (int rr = r; rr < 64; rr += 16) {
      union { u16 s[4]; u64 ll; } u;
      u.s[0] = f2bf(tile[c4][rr]);
      u.s[1] = f2bf(tile[c4 + 1][rr]);
      u.s[2] = f2bf(tile[c4 + 2][rr]);
      u.s[3] = f2bf(tile[c4 + 3][rr]);
      *(u64*)&Wt[(size_t)(bj * 64 + rr) * 1024 + bi * 64 + c4] = u.ll;
    }
    return;
  }
  // ---- role: per-batch stable partition of key tokens ----
  const int b = bid - 9216;
  const int lane = t & 63, w = t >> 6;
  int m8[8], c = 0;
  #pragma unroll
  for (int j = 0; j < 8; j++) {
    m8[j] = (mask[b * 2048 + t * 8 + j] == 1);
    c += m8[j];
  }
  int incl = c;
  #pragma unroll
  for (int off = 1; off < 64; off <<= 1) {
    int v = __shfl_up(incl, off);
    if (lane >= off) incl += v;
  }
  if (lane == 63) wtot[w] = incl;
  __syncthreads();
  if (t == 0) {
    int s = 0;
    for (int i = 0; i < 4; i++) { wbase[i] = s; s += wtot[i]; }
    wbase[4] = s;
  }
  __syncthreads();
  const int nk = wbase[4];
  int urun = wbase[w] + incl - c;
  #pragma unroll
  for (int j = 0; j < 8; j++) {
    int tok = t * 8 + j;
    int slot = m8[j] ? urun : nk + (tok - urun);
    s2t[b * 2048 + slot] = b * 2048 + tok;
    urun += m8[j];
  }
  if (t == 0) nkbuf[b] = nk;
}

// ---------- kernel 2: fused Q/K/V GEMM, XCD-swizzled, compacted K/V ----------
// Q role: m0=(sub&63)*128 (x-strip), n0=(sub>>6)*128 — same-strip blocks 64
// apart -> same XCD. K/V roles: slot-strips remapped so likely-DEAD strips
// (slot >= 1024; nk ~ Binom(2048,.5) ~ 1024) dispatch LAST within the role.
// Same-strip spacing 32 (%8==0) keeps XCD-L2 grouping.
// Q-role epilogue pre-multiplies by QSCALE so attention's exp is bare exp2(s).
__global__ __launch_bounds__(256, 4) void gemm_fused(const u16* __restrict__ xb,
                                                     const u16* __restrict__ wqkvt,
                                                     const int* __restrict__ s2t,
                                                     const int* __restrict__ nkbuf,
                                                     u16* __restrict__ qbuf,
                                                     u16* __restrict__ kc,
                                                     u16* __restrict__ vtc) {
  __shared__ u16 Asm[128 * 64];
  __shared__ u16 Bsm[128 * 64];
  const int bid = blockIdx.x;
  const int role = bid >> 9;            // 0=Q 1=K 2=V
  const int sub = bid & 511;
  const int tid = threadIdx.x, lane = tid & 63, w = tid >> 6;
  const int quad = lane >> 4, l15 = lane & 15;
  const int wm = (w >> 1) * 64, wn = (w & 1) * 64;
  const int srow = lane >> 3;
  const int gcc = ((lane & 7) ^ srow) * 8;
  const int rx8 = (l15 & 7);

  int m0, n0;
  if (role == 0) {
    m0 = (sub & 63) * 128; n0 = (sub >> 6) * 128;
  } else {
    // dead-likely slot strips (st>=8 within batch) go last: q=sub>>8 selects
    // high half-strips; strip = batch*16 + (m5&7) + q*8, bijective over 0..63.
    int q = sub >> 8, r = sub & 255;
    int e = r >> 5, m5 = r & 31;
    int strip = ((m5 >> 3) << 4) + (m5 & 7) + (q << 3);
    if (role == 1) { m0 = strip * 128; n0 = e * 128; }
    else           { m0 = e * 128; n0 = strip * 128; }
  }
  if (role == 1 && (m0 & 2047) >= nkbuf[m0 >> 11]) return;
  if (role == 2 && (n0 & 2047) >= nkbuf[n0 >> 11]) return;

  // per-lane source row ids for the 4 staged chunks
  int arow[4], brow[4];
  #pragma unroll
  for (int c = 0; c < 4; ++c) {
    int rit = (w * 4 + c) * 8 + srow;   // row within the 128-tile
    if (role == 0)      { arow[c] = m0 + rit;            brow[c] = n0 + rit; }
    else if (role == 1) { arow[c] = s2t[m0 + rit];       brow[c] = 1024 + n0 + rit; }
    else                { arow[c] = 2048 + m0 + rit;     brow[c] = s2t[n0 + rit]; }
  }
  const u16 *Asrc = (role == 2) ? wqkvt : xb;
  const u16 *Bsrc = (role == 2) ? xb : wqkvt;

  f32x4 acc[4][4];
  #pragma unroll
  for (int i = 0; i < 4; i++)
    #pragma unroll
    for (int j = 0; j < 4; j++)
      #pragma unroll
      for (int r = 0; r < 4; r++) acc[i][j][r] = 0.f;

  for (int kt = 0; kt < 1024; kt += 64) {
    __syncthreads();
    #pragma unroll
    for (int c = 0; c < 4; ++c) {
      int chunk = w * 4 + c;
      glds16(&Asm[chunk * 512], &Asrc[(size_t)arow[c] * 1024 + kt + gcc]);
      glds16(&Bsm[chunk * 512], &Bsrc[(size_t)brow[c] * 1024 + kt + gcc]);
    }
    __syncthreads();
    #pragma unroll
    for (int ks = 0; ks < 2; ++ks) {
      int pc = ((ks * 4 + quad) ^ rx8) * 8;
      short8 av[4], bv[4];
      #pragma unroll
      for (int i = 0; i < 4; i++)
        av[i] = *(const short8*)&Asm[(wm + i * 16 + l15) * 64 + pc];
      #pragma unroll
      for (int j = 0; j < 4; j++)
        bv[j] = *(const short8*)&Bsm[(wn + j * 16 + l15) * 64 + pc];
      #pragma unroll
      for (int i = 0; i < 4; i++)
        #pragma unroll
        for (int j = 0; j < 4; j++)
          acc[i][j] = MFMA(av[i], bv[j], acc[i][j]);
    }
  }

  if (role == 2) {
    #pragma unroll
    for (int j = 0; j < 4; j++) {
      int col = n0 + wn + j * 16 + l15;           // global slot 0..8191
      int bb = col >> 11, sl = col & 2047;
      #pragma unroll
      for (int i = 0; i < 4; i++)
        #pragma unroll
        for (int r = 0; r < 4; r++) {
          int row = m0 + wm + i * 16 + quad * 4 + r;   // d in 0..1023
          vtc[(size_t)(bb * 1024 + row) * 2048 + sl] = f2bf(acc[i][j][r]);
        }
    }
  } else {
    u16* dst = (role == 0) ? qbuf : kc;
    const float sc = (role == 0) ? QSCALE : 1.f;
    #pragma unroll
    for (int i = 0; i < 4; i++)
      #pragma unroll
      for (int j = 0; j < 4; j++) {
        int col = n0 + wn + j * 16 + l15;
        #pragma unroll
        for (int r = 0; r < 4; r++) {
          int row = m0 + wm + i * 16 + quad * 4 + r;
          dst[(size_t)row * 1024 + col] = f2bf(acc[i][j][r] * sc);
        }
      }
  }
}

// ---------- kernel 3: flash attention, register P, BK=128, MFMA row-sums ----------
// T5: s_setprio(1) around MFMA clusters — attn blocks are independent (2/CU,
// no inter-block lockstep) so scheduler arbitration pays here (m191: +4-7%);
// NOT applied to the lockstep GEMMs (m190: hurts).
__global__ __launch_bounds__(256, 2) void attn_kernel(const u16* __restrict__ q,
                                                      const u16* __restrict__ kc,
                                                      const u16* __restrict__ vtc,
                                                      const int* __restrict__ nkbuf,
                                                      u16* __restrict__ ao) {
  __shared__ u16 Ksm[2][64 * 64];       // π-permuted key rows, swizzled cols (d)
  __shared__ u16 Vsm[2][64 * 64];       // [d][k_local] linear keys, swizzled
  const int h = blockIdx.x, b = blockIdx.y, qt = blockIdx.z;
  const int tid = threadIdx.x, lane = tid & 63, w = tid >> 6;
  const int quad = lane >> 4, l15 = lane & 15;
  const int q0 = qt * 256 + w * 64;     // wave's q base within batch
  const int srow = lane >> 3;
  const int gcc = ((lane & 7) ^ srow) * 8;
  const int rx8 = (l15 & 7);
  const int nk = nkbuf[b];
  const int nt2 = (nk + 127) >> 7;
  const int quad8 = quad * 8;

  // staging rows + π for K source
  int vrow[2], prow[2];
  #pragma unroll
  for (int c = 0; c < 2; ++c) {
    int row = (w * 2 + c) * 8 + srow;
    vrow[c] = row;
    prow[c] = ((row >> 4) & 1) * 32 + ((row >> 2) & 3) * 8 + ((row >> 5) & 1) * 4 + (row & 3);
  }

  // ones B-fragment (bf16 1.0 splat) for MFMA row-sums
  short8 ones;
  #pragma unroll
  for (int z = 0; z < 8; z++) ones[z] = (short)0x3F80;

  // Q fragments (B-operand): n=q=l15(+16i), k=d=quad*8+j (+32ks)
  short8 qf[4][2];
  #pragma unroll
  for (int i = 0; i < 4; i++)
    #pragma unroll
    for (int ks = 0; ks < 2; ks++)
      qf[i][ks] = *(const short8*)&q[(size_t)(b * 2048 + q0 + i * 16 + l15) * 1024 +
                                     h * 64 + ks * 32 + quad * 8];

  f32x4 o[4][4], osum[4];
  #pragma unroll
  for (int i = 0; i < 4; i++) {
    #pragma unroll
    for (int r = 0; r < 4; r++) osum[i][r] = 0.f;
    #pragma unroll
    for (int jd = 0; jd < 4; jd++)
      #pragma unroll
      for (int r = 0; r < 4; r++) o[i][jd][r] = 0.f;
  }

#define SUBTILE(st_, kbase_)                                                           \
  {                                                                                    \
    f32x4 s[4][4];                                                                     \
    _Pragma("unroll") for (int j = 0; j < 4; j++)                                      \
      _Pragma("unroll") for (int i = 0; i < 4; i++)                                    \
        _Pragma("unroll") for (int r = 0; r < 4; r++) s[j][i][r] = 0.f;                \
    _Pragma("unroll") for (int ks = 0; ks < 2; ks++) {                                 \
      int pc = ((ks * 4 + quad) ^ rx8) * 8;                                            \
      short8 kf[4];                                                                    \
      _Pragma("unroll") for (int j = 0; j < 4; j++)                                    \
        kf[j] = *(const short8*)&Ksm[st_][(j * 16 + l15) * 64 + pc];                   \
      __builtin_amdgcn_s_setprio(1);                                                   \
      _Pragma("unroll") for (int j = 0; j < 4; j++)                                    \
        _Pragma("unroll") for (int i = 0; i < 4; i++)                                  \
          s[j][i] = MFMA(kf[j], qf[i][ks], s[j][i]);                                   \
      __builtin_amdgcn_s_setprio(0);                                                   \
    }                                                                                  \
    const bool tail = ((kbase_) + 64 > nk);                                            \
    short8 pf[4][2];                                                                   \
    _Pragma("unroll") for (int i = 0; i < 4; i++) {                                    \
      float p[4][4];                                                                   \
      if (!tail) {                                                                     \
        _Pragma("unroll") for (int j = 0; j < 4; j++)                                  \
          _Pragma("unroll") for (int r = 0; r < 4; r++)                                \
            p[j][r] = fexp2(s[j][i][r]);                                               \
      } else {                                                                         \
        _Pragma("unroll") for (int j = 0; j < 4; j++)                                  \
          _Pragma("unroll") for (int r = 0; r < 4; r++) {                              \
            int slot = (kbase_) + (j & 1) * 32 + quad8 + (j >> 1) * 4 + r;             \
            float e = fexp2(s[j][i][r]);                                               \
            p[j][r] = (slot < nk) ? e : 0.f;                                           \
          }                                                                            \
      }                                                                                \
      _Pragma("unroll") for (int ks = 0; ks < 2; ks++) {                               \
        union { u32 u[4]; short8 v; } pk;                                              \
        u32 a0 = __builtin_bit_cast(u32, p[ks][0]) + 0x8000u;                          \
        u32 a1 = __builtin_bit_cast(u32, p[ks][1]) + 0x8000u;                          \
        u32 a2 = __builtin_bit_cast(u32, p[ks][2]) + 0x8000u;                          \
        u32 a3 = __builtin_bit_cast(u32, p[ks][3]) + 0x8000u;                          \
        u32 b0 = __builtin_bit_cast(u32, p[ks + 2][0]) + 0x8000u;                      \
        u32 b1 = __builtin_bit_cast(u32, p[ks + 2][1]) + 0x8000u;                      \
        u32 b2 = __builtin_bit_cast(u32, p[ks + 2][2]) + 0x8000u;                      \
        u32 b3 = __builtin_bit_cast(u32, p[ks + 2][3]) + 0x8000u;                      \
        pk.u[0] = __builtin_amdgcn_perm(a1, a0, 0x07060302u);                          \
        pk.u[1] = __builtin_amdgcn_perm(a3, a2, 0x07060302u);                          \
        pk.u[2] = __builtin_amdgcn_perm(b1, b0, 0x07060302u);                          \
        pk.u[3] = __builtin_amdgcn_perm(b3, b2, 0x07060302u);                          \
        pf[i][ks] = pk.v;                                                              \
      }                                                                                \
    }                                                                                  \
    _Pragma("unroll") for (int ks = 0; ks < 2; ks++) {                                 \
      int pcv = ((ks * 4 + quad) ^ rx8) * 8;                                           \
      short8 vf[4];                                                                    \
      _Pragma("unroll") for (int jd = 0; jd < 4; jd++)                                 \
        vf[jd] = *(const short8*)&Vsm[st_][(jd * 16 + l15) * 64 + pcv];                \
      __builtin_amdgcn_s_setprio(1);                                                   \
      _Pragma("unroll") for (int i = 0; i < 4; i++) {                                  \
        osum[i] = MFMA(pf[i][ks], ones, osum[i]);                                      \
        _Pragma("unroll") for (int jd = 0; jd < 4; jd++)                               \
          o[i][jd] = MFMA(pf[i][ks], vf[jd], o[i][jd]);                                \
      }                                                                                \
      __builtin_amdgcn_s_setprio(0);                                                   \
    }                                                                                  \
  }

  for (int t = 0; t < nt2; ++t) {
    const int k0 = t * 128;
    __syncthreads();
    #pragma unroll
    for (int c = 0; c < 2; ++c) {
      int chunk = w * 2 + c;
      glds16(&Ksm[0][chunk * 512],
             &kc[(size_t)(b * 2048 + k0 + prow[c]) * 1024 + h * 64 + gcc]);
      glds16(&Vsm[0][chunk * 512],
             &vtc[(size_t)(b * 1024 + h * 64 + vrow[c]) * 2048 + k0 + gcc]);
      glds16(&Ksm[1][chunk * 512],
             &kc[(size_t)(b * 2048 + k0 + 64 + prow[c]) * 1024 + h * 64 + gcc]);
      glds16(&Vsm[1][chunk * 512],
             &vtc[(size_t)(b * 1024 + h * 64 + vrow[c]) * 2048 + k0 + 64 + gcc]);
    }
    __syncthreads();

    SUBTILE(0, k0)
    if (k0 + 64 < nk) SUBTILE(1, k0 + 64)
  }
#undef SUBTILE

  // epilogue: osum rows == o rows (quad*4+r) — direct normalize, no shuffles
  #pragma unroll
  for (int i = 0; i < 4; i++)
    #pragma unroll
    for (int r = 0; r < 4; r++) {
      float inv = 1.f / osum[i][r];
      size_t row = (size_t)(b * 2048 + q0 + i * 16 + quad * 4 + r);
      #pragma unroll
      for (int jd = 0; jd < 4; jd++)
        ao[row * 1024 + h * 64 + jd * 16 + l15] = f2bf(o[i][jd][r] * inv);
    }
}

// ---------- kernel 4: output projection + bias (XCD-swizzled flat grid) ----------
// 512 blocks: m0=(bid&63)*128 (aobuf strip, 16MB operand), n0=(bid>>6)*128.
__global__ __launch_bounds__(256, 3) void gemm_proj(const u16* __restrict__ A,
                                                    const u16* __restrict__ Bt,
                                                    const float* __restrict__ bias,
                                                    float* __restrict__ out) {
  __shared__ u16 Asm[128 * 64];
  __shared__ u16 Bsm[128 * 64];
  const int tid = threadIdx.x, lane = tid & 63, w = tid >> 6;
  const int quad = lane >> 4, l15 = lane & 15;
  const int m0 = (blockIdx.x & 63) * 128, n0 = (blockIdx.x >> 6) * 128;
  const int wm = (w >> 1) * 64, wn = (w & 1) * 64;
  const int srow = lane >> 3;
  const int gcc = ((lane & 7) ^ srow) * 8;
  const int rx8 = (l15 & 7);
  f32x4 acc[4][4];
  #pragma unroll
  for (int i = 0; i < 4; i++)
    #pragma unroll
    for (int j = 0; j < 4; j++)
      #pragma unroll
      for (int r = 0; r < 4; r++) acc[i][j][r] = 0.f;

  for (int kt = 0; kt < 1024; kt += 64) {
    __syncthreads();
    #pragma unroll
    for (int c = 0; c < 4; ++c) {
      int chunk = w * 4 + c;
      int row = chunk * 8 + srow;
      glds16(&Asm[chunk * 512], &A[(size_t)(m0 + row) * 1024 + kt + gcc]);
      glds16(&Bsm[chunk * 512], &Bt[(size_t)(n0 + row) * 1024 + kt + gcc]);
    }
    __syncthreads();
    #pragma unroll
    for (int ks = 0; ks < 2; ++ks) {
      int pc = ((ks * 4 + quad) ^ rx8) * 8;
      short8 av[4], bv[4];
      #pragma unroll
      for (int i = 0; i < 4; i++)
        av[i] = *(const short8*)&Asm[(wm + i * 16 + l15) * 64 + pc];
      #pragma unroll
      for (int j = 0; j < 4; j++)
        bv[j] = *(const short8*)&Bsm[(wn + j * 16 + l15) * 64 + pc];
      #pragma unroll
      for (int i = 0; i < 4; i++)
        #pragma unroll
        for (int j = 0; j < 4; j++)
          acc[i][j] = MFMA(av[i], bv[j], acc[i][j]);
    }
  }

  #pragma unroll
  for (int j = 0; j < 4; j++) {
    int col = n0 + wn + j * 16 + l15;
    float bj = bias[col];
    #pragma unroll
    for (int i = 0; i < 4; i++) {
      #pragma unroll
      for (int r = 0; r < 4; r++) {
        int row = m0 + wm + i * 16 + quad * 4 + r;
        out[(size_t)row * 1024 + col] = acc[i][j][r] + bj;
      }
    }
  }
}

// ---------- launch ----------
extern "C" void kernel_launch(void* const* d_in, const int* in_sizes, int n_in,
                              void* d_out, int out_size, void* d_ws, size_t ws_size,
                              hipStream_t stream) {
  (void)in_sizes; (void)n_in; (void)out_size; (void)ws_size;
  const float* x     = (const float*)d_in[0];
  const int*   mask  = (const int*)d_in[1];
  const float* Wqkv  = (const float*)d_in[2];
  const float* Wproj = (const float*)d_in[3];
  const float* bproj = (const float*)d_in[4];
  float* out = (float*)d_out;
  char* ws = (char*)d_ws;

  size_t off = 0;
  u16* xb     = (u16*)(ws + off); off += 8192ull * 1024 * 2;   // x bf16; REUSED as aobuf
  u16* wqkvt  = (u16*)(ws + off); off += 3072ull * 1024 * 2;   // Wqkv^T bf16 [3072][1024]
  u16* wprojt = (u16*)(ws + off); off += 1024ull * 1024 * 2;   // Wproj^T bf16 [1024][1024]
  u16* qbuf   = (u16*)(ws + off); off += 8192ull * 1024 * 2;   // Q (pre-scaled) bf16
  u16* kcbuf  = (u16*)(ws + off); off += 4096ull * 2048 * 2;   // K compact [b][slot][1024]
  u16* vtcbuf = (u16*)(ws + off); off += 4096ull * 2048 * 2;   // V^T compact [b][d][slot]
  int* s2t    = (int*)(ws + off); off += 8192ull * 4;          // slot -> global token
  int* nkbuf  = (int*)(ws + off); off += 4 * 4;                // per-batch nk
  u16* aobuf  = xb;   // xb's last read is gemm_fused; attn writes ao after -> safe alias

  prep<<<9220, 256, 0, stream>>>(x, mask, Wqkv, Wproj, xb, wqkvt, wprojt, s2t, nkbuf);
  gemm_fused<<<1536, 256, 0, stream>>>(xb, wqkvt, s2t, nkbuf, qbuf, kcbuf, vtcbuf);
  attn_kernel<<<dim3(16, 4, 8), 256, 0, stream>>>(qbuf, kcbuf, vtcbuf, nkbuf, aobuf);
  gemm_proj<<<512, 256, 0, stream>>>(aobuf, wprojt, bproj, out);
}

// Round 4
// 206.389 us; speedup vs baseline: 1.4518x; 1.0100x over previous
//
#include <hip/hip_runtime.h>

typedef unsigned short u16;
typedef unsigned int u32;
typedef unsigned long long u64;
typedef __attribute__((ext_vector_type(8))) short short8;
typedef __attribute__((ext_vector_type(4))) float f32x4;

#define QSCALE 0.18033688f   /* 0.125 * log2(e), folded into Q at projection */

// ---------- helpers ----------
__device__ __forceinline__ u16 f2bf(float f) {
  u32 u = __builtin_bit_cast(u32, f);
  u += 0x7fffu + ((u >> 16) & 1u);   // RNE
  return (u16)(u >> 16);
}

__device__ __forceinline__ float fexp2(float x) {
#if __has_builtin(__builtin_amdgcn_exp2f)
  return __builtin_amdgcn_exp2f(x);   // v_exp_f32
#else
  return exp2f(x);
#endif
}

// async global->LDS, 16B per lane. LDS dest is wave-uniform base + lane*16.
__device__ __forceinline__ void glds16(u16* lds, const u16* g) {
  __builtin_amdgcn_global_load_lds(
      (const __attribute__((address_space(1))) u32*)g,
      (__attribute__((address_space(3))) u32*)lds, 16, 0, 0);
}

#define MFMA(a, b, c) __builtin_amdgcn_mfma_f32_16x16x32_bf16((a), (b), (c), 0, 0, 0)

// LDS tile layout (XOR-swizzled), tile = [64 rows][64 u16 cols] = 8 KiB:
//   physical 16B-chunk slot p of row r holds logical col-chunk (p ^ (r&7)).
//
// JOURNAL:
// R2: __launch_bounds__(256,5) forced VGPR 64->48 -> acc spill to scratch
//     (WRITE 34->271MB, 51->146us). Keep (256,4); residency was LDS-limited.
// R3: dead-last strip remap on K/V roles cost ~5us on gemm_fused (56.5 vs
//     51.4) -> reverted to R0 mapping here.
// R4 (this): 2-phase LDS double-buffer (stage t+1 before compute t, ONE
//     barrier/tile) applied ONLY to the low-TLP kernels: attn (2 blk/CU) and
//     gemm_proj (512 blk = 2/CU). NOT to gemm_fused (6/CU; m99/m100: neutral).

// ---------- kernel 1: fused prep (x cvt | W transposes | mask scan) ----------
__global__ __launch_bounds__(256) void prep(const float* __restrict__ x,
                                            const int* __restrict__ mask,
                                            const float* __restrict__ Wqkv,
                                            const float* __restrict__ Wproj,
                                            u16* __restrict__ xb,
                                            u16* __restrict__ wqkvt,
                                            u16* __restrict__ wprojt,
                                            int* __restrict__ s2t,
                                            int* __restrict__ nkbuf) {
  __shared__ float tile[64][65];
  __shared__ int wtot[4];
  __shared__ int wbase[5];
  const int bid = blockIdx.x, t = threadIdx.x;

  if (bid < 8192) {                    // ---- role: x fp32 -> bf16 ----
    int i = bid * 256 + t;
    float4 v = ((const float4*)x)[i];
    union { u16 s[4]; u64 ll; } u;
    u.s[0] = f2bf(v.x); u.s[1] = f2bf(v.y); u.s[2] = f2bf(v.z); u.s[3] = f2bf(v.w);
    ((u64*)xb)[i] = u.ll;
    return;
  }
  if (bid < 9216) {                    // ---- role: W transpose+cvt ----
    const float* Wm; u16* Wt; int Cc, bj, bi;
    if (bid < 8960) { int tt = bid - 8192; Wm = Wqkv;  Wt = wqkvt;  Cc = 3072; bj = tt % 48; bi = tt / 48; }
    else            { int tt = bid - 8960; Wm = Wproj; Wt = wprojt; Cc = 1024; bj = tt & 15; bi = tt >> 4; }
    const int r = t >> 4, c4 = (t & 15) << 2;
    for (int rr = r; rr < 64; rr += 16) {
      float4 v = *(const float4*)&Wm[(size_t)(bi * 64 + rr) * Cc + bj * 64 + c4];
      tile[rr][c4] = v.x; tile[rr][c4 + 1] = v.y; tile[rr][c4 + 2] = v.z; tile[rr][c4 + 3] = v.w;
    }
    __syncthreads();
    for (int rr = r; rr < 64; rr += 16) {
      union { u16 s[4]; u64 ll; } u;
      u.s[0] = f2bf(tile[c4][rr]);
      u.s[1] = f2bf(tile[c4 + 1][rr]);
      u.s[2] = f2bf(tile[c4 + 2][rr]);
      u.s[3] = f2bf(tile[c4 + 3][rr]);
      *(u64*)&Wt[(size_t)(bj * 64 + rr) * 1024 + bi * 64 + c4] = u.ll;
    }
    return;
  }
  // ---- role: per-batch stable partition of key tokens ----
  const int b = bid - 9216;
  const int lane = t & 63, w = t >> 6;
  int m8[8], c = 0;
  #pragma unroll
  for (int j = 0; j < 8; j++) {
    m8[j] = (mask[b * 2048 + t * 8 + j] == 1);
    c += m8[j];
  }
  int incl = c;
  #pragma unroll
  for (int off = 1; off < 64; off <<= 1) {
    int v = __shfl_up(incl, off);
    if (lane >= off) incl += v;
  }
  if (lane == 63) wtot[w] = incl;
  __syncthreads();
  if (t == 0) {
    int s = 0;
    for (int i = 0; i < 4; i++) { wbase[i] = s; s += wtot[i]; }
    wbase[4] = s;
  }
  __syncthreads();
  const int nk = wbase[4];
  int urun = wbase[w] + incl - c;
  #pragma unroll
  for (int j = 0; j < 8; j++) {
    int tok = t * 8 + j;
    int slot = m8[j] ? urun : nk + (tok - urun);
    s2t[b * 2048 + slot] = b * 2048 + tok;
    urun += m8[j];
  }
  if (t == 0) nkbuf[b] = nk;
}

// ---------- kernel 2: fused Q/K/V GEMM, XCD-swizzled, compacted K/V ----------
// Q/K roles: m0=(sub&63)*128 (x-strip), n0=(sub>>6)*128 — same-strip blocks
// 64 apart -> same XCD. V role mirrored. (R0 mapping, best measured.)
// Q-role epilogue pre-multiplies by QSCALE so attention's exp is bare exp2(s).
__global__ __launch_bounds__(256, 4) void gemm_fused(const u16* __restrict__ xb,
                                                     const u16* __restrict__ wqkvt,
                                                     const int* __restrict__ s2t,
                                                     const int* __restrict__ nkbuf,
                                                     u16* __restrict__ qbuf,
                                                     u16* __restrict__ kc,
                                                     u16* __restrict__ vtc) {
  __shared__ u16 Asm[128 * 64];
  __shared__ u16 Bsm[128 * 64];
  const int bid = blockIdx.x;
  const int role = bid >> 9;            // 0=Q 1=K 2=V
  const int sub = bid & 511;
  const int tid = threadIdx.x, lane = tid & 63, w = tid >> 6;
  const int quad = lane >> 4, l15 = lane & 15;
  const int wm = (w >> 1) * 64, wn = (w & 1) * 64;
  const int srow = lane >> 3;
  const int gcc = ((lane & 7) ^ srow) * 8;
  const int rx8 = (l15 & 7);

  int m0, n0;
  if (role == 2) { m0 = (sub >> 6) * 128; n0 = (sub & 63) * 128; }
  else           { m0 = (sub & 63) * 128; n0 = (sub >> 6) * 128; }
  if (role == 1 && (m0 & 2047) >= nkbuf[m0 >> 11]) return;
  if (role == 2 && (n0 & 2047) >= nkbuf[n0 >> 11]) return;

  // per-lane source row ids for the 4 staged chunks
  int arow[4], brow[4];
  #pragma unroll
  for (int c = 0; c < 4; ++c) {
    int rit = (w * 4 + c) * 8 + srow;   // row within the 128-tile
    if (role == 0)      { arow[c] = m0 + rit;            brow[c] = n0 + rit; }
    else if (role == 1) { arow[c] = s2t[m0 + rit];       brow[c] = 1024 + n0 + rit; }
    else                { arow[c] = 2048 + m0 + rit;     brow[c] = s2t[n0 + rit]; }
  }
  const u16 *Asrc = (role == 2) ? wqkvt : xb;
  const u16 *Bsrc = (role == 2) ? xb : wqkvt;

  f32x4 acc[4][4];
  #pragma unroll
  for (int i = 0; i < 4; i++)
    #pragma unroll
    for (int j = 0; j < 4; j++)
      #pragma unroll
      for (int r = 0; r < 4; r++) acc[i][j][r] = 0.f;

  for (int kt = 0; kt < 1024; kt += 64) {
    __syncthreads();
    #pragma unroll
    for (int c = 0; c < 4; ++c) {
      int chunk = w * 4 + c;
      glds16(&Asm[chunk * 512], &Asrc[(size_t)arow[c] * 1024 + kt + gcc]);
      glds16(&Bsm[chunk * 512], &Bsrc[(size_t)brow[c] * 1024 + kt + gcc]);
    }
    __syncthreads();
    #pragma unroll
    for (int ks = 0; ks < 2; ++ks) {
      int pc = ((ks * 4 + quad) ^ rx8) * 8;
      short8 av[4], bv[4];
      #pragma unroll
      for (int i = 0; i < 4; i++)
        av[i] = *(const short8*)&Asm[(wm + i * 16 + l15) * 64 + pc];
      #pragma unroll
      for (int j = 0; j < 4; j++)
        bv[j] = *(const short8*)&Bsm[(wn + j * 16 + l15) * 64 + pc];
      #pragma unroll
      for (int i = 0; i < 4; i++)
        #pragma unroll
        for (int j = 0; j < 4; j++)
          acc[i][j] = MFMA(av[i], bv[j], acc[i][j]);
    }
  }

  if (role == 2) {
    #pragma unroll
    for (int j = 0; j < 4; j++) {
      int col = n0 + wn + j * 16 + l15;           // global slot 0..8191
      int bb = col >> 11, sl = col & 2047;
      #pragma unroll
      for (int i = 0; i < 4; i++)
        #pragma unroll
        for (int r = 0; r < 4; r++) {
          int row = m0 + wm + i * 16 + quad * 4 + r;   // d in 0..1023
          vtc[(size_t)(bb * 1024 + row) * 2048 + sl] = f2bf(acc[i][j][r]);
        }
    }
  } else {
    u16* dst = (role == 0) ? qbuf : kc;
    const float sc = (role == 0) ? QSCALE : 1.f;
    #pragma unroll
    for (int i = 0; i < 4; i++)
      #pragma unroll
      for (int j = 0; j < 4; j++) {
        int col = n0 + wn + j * 16 + l15;
        #pragma unroll
        for (int r = 0; r < 4; r++) {
          int row = m0 + wm + i * 16 + quad * 4 + r;
          dst[(size_t)row * 1024 + col] = f2bf(acc[i][j][r] * sc);
        }
      }
  }
}

// ---------- kernel 3: flash attention, 2-phase double-buffered K/V ----------
// Regime: 2 blocks/CU, 32KB staged per 128-K-tile -> stage latency WAS on the
// critical path (sync;stage;sync;compute). Now: stage(t+1 -> buf^1) issued
// BEFORE compute(t, buf); ONE __syncthreads per tile (its vmcnt(0)+barrier
// guarantees t+1's data landed and all reads of buf are done). T5 setprio
// kept around MFMA clusters (independent blocks; m191 regime).
__global__ __launch_bounds__(256, 2) void attn_kernel(const u16* __restrict__ q,
                                                      const u16* __restrict__ kc,
                                                      const u16* __restrict__ vtc,
                                                      const int* __restrict__ nkbuf,
                                                      u16* __restrict__ ao) {
  __shared__ u16 Ksm[2][2][64 * 64];    // [pipe buf][subtile] π-permuted keys
  __shared__ u16 Vsm[2][2][64 * 64];    // [pipe buf][subtile] [d][k_local]
  const int h = blockIdx.x, b = blockIdx.y, qt = blockIdx.z;
  const int tid = threadIdx.x, lane = tid & 63, w = tid >> 6;
  const int quad = lane >> 4, l15 = lane & 15;
  const int q0 = qt * 256 + w * 64;     // wave's q base within batch
  const int srow = lane >> 3;
  const int gcc = ((lane & 7) ^ srow) * 8;
  const int rx8 = (l15 & 7);
  const int nk = nkbuf[b];
  const int nt2 = (nk + 127) >> 7;
  const int quad8 = quad * 8;

  // staging rows + π for K source
  int vrow[2], prow[2];
  #pragma unroll
  for (int c = 0; c < 2; ++c) {
    int row = (w * 2 + c) * 8 + srow;
    vrow[c] = row;
    prow[c] = ((row >> 4) & 1) * 32 + ((row >> 2) & 3) * 8 + ((row >> 5) & 1) * 4 + (row & 3);
  }

  // ones B-fragment (bf16 1.0 splat) for MFMA row-sums
  short8 ones;
  #pragma unroll
  for (int z = 0; z < 8; z++) ones[z] = (short)0x3F80;

  // Q fragments (B-operand): n=q=l15(+16i), k=d=quad*8+j (+32ks)
  short8 qf[4][2];
  #pragma unroll
  for (int i = 0; i < 4; i++)
    #pragma unroll
    for (int ks = 0; ks < 2; ks++)
      qf[i][ks] = *(const short8*)&q[(size_t)(b * 2048 + q0 + i * 16 + l15) * 1024 +
                                     h * 64 + ks * 32 + quad * 8];

  f32x4 o[4][4], osum[4];
  #pragma unroll
  for (int i = 0; i < 4; i++) {
    #pragma unroll
    for (int r = 0; r < 4; r++) osum[i][r] = 0.f;
    #pragma unroll
    for (int jd = 0; jd < 4; jd++)
      #pragma unroll
      for (int r = 0; r < 4; r++) o[i][jd][r] = 0.f;
  }

#define STAGEKV(pb_, t_) {                                                             \
    const int k0s = (t_) * 128;                                                        \
    _Pragma("unroll") for (int c = 0; c < 2; ++c) {                                    \
      int chunk = w * 2 + c;                                                           \
      glds16(&Ksm[pb_][0][chunk * 512],                                                \
             &kc[(size_t)(b * 2048 + k0s + prow[c]) * 1024 + h * 64 + gcc]);           \
      glds16(&Vsm[pb_][0][chunk * 512],                                                \
             &vtc[(size_t)(b * 1024 + h * 64 + vrow[c]) * 2048 + k0s + gcc]);          \
      glds16(&Ksm[pb_][1][chunk * 512],                                                \
             &kc[(size_t)(b * 2048 + k0s + 64 + prow[c]) * 1024 + h * 64 + gcc]);      \
      glds16(&Vsm[pb_][1][chunk * 512],                                                \
             &vtc[(size_t)(b * 1024 + h * 64 + vrow[c]) * 2048 + k0s + 64 + gcc]);     \
    }                                                                                  \
  }

#define SUBTILE(pb_, st_, kbase_)                                                      \
  {                                                                                    \
    f32x4 s[4][4];                                                                     \
    _Pragma("unroll") for (int j = 0; j < 4; j++)                                      \
      _Pragma("unroll") for (int i = 0; i < 4; i++)                                    \
        _Pragma("unroll") for (int r = 0; r < 4; r++) s[j][i][r] = 0.f;                \
    _Pragma("unroll") for (int ks = 0; ks < 2; ks++) {                                 \
      int pc = ((ks * 4 + quad) ^ rx8) * 8;                                            \
      short8 kf[4];                                                                    \
      _Pragma("unroll") for (int j = 0; j < 4; j++)                                    \
        kf[j] = *(const short8*)&Ksm[pb_][st_][(j * 16 + l15) * 64 + pc];              \
      __builtin_amdgcn_s_setprio(1);                                                   \
      _Pragma("unroll") for (int j = 0; j < 4; j++)                                    \
        _Pragma("unroll") for (int i = 0; i < 4; i++)                                  \
          s[j][i] = MFMA(kf[j], qf[i][ks], s[j][i]);                                   \
      __builtin_amdgcn_s_setprio(0);                                                   \
    }                                                                                  \
    const bool tail = ((kbase_) + 64 > nk);                                            \
    short8 pf[4][2];                                                                   \
    _Pragma("unroll") for (int i = 0; i < 4; i++) {                                    \
      float p[4][4];                                                                   \
      if (!tail) {                                                                     \
        _Pragma("unroll") for (int j = 0; j < 4; j++)                                  \
          _Pragma("unroll") for (int r = 0; r < 4; r++)                                \
            p[j][r] = fexp2(s[j][i][r]);                                               \
      } else {                                                                         \
        _Pragma("unroll") for (int j = 0; j < 4; j++)                                  \
          _Pragma("unroll") for (int r = 0; r < 4; r++) {                              \
            int slot = (kbase_) + (j & 1) * 32 + quad8 + (j >> 1) * 4 + r;             \
            float e = fexp2(s[j][i][r]);                                               \
            p[j][r] = (slot < nk) ? e : 0.f;                                           \
          }                                                                            \
      }                                                                                \
      _Pragma("unroll") for (int ks = 0; ks < 2; ks++) {                               \
        union { u32 u[4]; short8 v; } pk;                                              \
        u32 a0 = __builtin_bit_cast(u32, p[ks][0]) + 0x8000u;                          \
        u32 a1 = __builtin_bit_cast(u32, p[ks][1]) + 0x8000u;                          \
        u32 a2 = __builtin_bit_cast(u32, p[ks][2]) + 0x8000u;                          \
        u32 a3 = __builtin_bit_cast(u32, p[ks][3]) + 0x8000u;                          \
        u32 b0 = __builtin_bit_cast(u32, p[ks + 2][0]) + 0x8000u;                      \
        u32 b1 = __builtin_bit_cast(u32, p[ks + 2][1]) + 0x8000u;                      \
        u32 b2 = __builtin_bit_cast(u32, p[ks + 2][2]) + 0x8000u;                      \
        u32 b3 = __builtin_bit_cast(u32, p[ks + 2][3]) + 0x8000u;                      \
        pk.u[0] = __builtin_amdgcn_perm(a1, a0, 0x07060302u);                          \
        pk.u[1] = __builtin_amdgcn_perm(a3, a2, 0x07060302u);                          \
        pk.u[2] = __builtin_amdgcn_perm(b1, b0, 0x07060302u);                          \
        pk.u[3] = __builtin_amdgcn_perm(b3, b2, 0x07060302u);                          \
        pf[i][ks] = pk.v;                                                              \
      }                                                                                \
    }                                                                                  \
    _Pragma("unroll") for (int ks = 0; ks < 2; ks++) {                                 \
      int pcv = ((ks * 4 + quad) ^ rx8) * 8;                                           \
      short8 vf[4];                                                                    \
      _Pragma("unroll") for (int jd = 0; jd < 4; jd++)                                 \
        vf[jd] = *(const short8*)&Vsm[pb_][st_][(jd * 16 + l15) * 64 + pcv];           \
      __builtin_amdgcn_s_setprio(1);                                                   \
      _Pragma("unroll") for (int i = 0; i < 4; i++) {                                  \
        osum[i] = MFMA(pf[i][ks], ones, osum[i]);                                      \
        _Pragma("unroll") for (int jd = 0; jd < 4; jd++)                               \
          o[i][jd] = MFMA(pf[i][ks], vf[jd], o[i][jd]);                                \
      }                                                                                \
      __builtin_amdgcn_s_setprio(0);                                                   \
    }                                                                                  \
  }

  // prologue: stage tile 0 into pipe-buf 0
  STAGEKV(0, 0)
  __syncthreads();
  for (int t = 0; t < nt2; ++t) {
    const int k0 = t * 128;
    const int pb = t & 1;
    if (t + 1 < nt2) STAGEKV(pb ^ 1, t + 1)
    SUBTILE(pb, 0, k0)
    if (k0 + 64 < nk) SUBTILE(pb, 1, k0 + 64)
    __syncthreads();   // vmcnt(0): t+1 staged; barrier: all reads of pb done
  }
#undef SUBTILE
#undef STAGEKV

  // epilogue: osum rows == o rows (quad*4+r) — direct normalize, no shuffles
  #pragma unroll
  for (int i = 0; i < 4; i++)
    #pragma unroll
    for (int r = 0; r < 4; r++) {
      float inv = 1.f / osum[i][r];
      size_t row = (size_t)(b * 2048 + q0 + i * 16 + quad * 4 + r);
      #pragma unroll
      for (int jd = 0; jd < 4; jd++)
        ao[row * 1024 + h * 64 + jd * 16 + l15] = f2bf(o[i][jd][r] * inv);
    }
}

// ---------- kernel 4: output projection + bias, 2-phase double-buffered ----------
// 512 blocks = 2/CU -> no cross-block cover; stage(kt+64 -> buf^1) issued
// before compute(buf), one barrier per K-step.
__global__ __launch_bounds__(256, 3) void gemm_proj(const u16* __restrict__ A,
                                                    const u16* __restrict__ Bt,
                                                    const float* __restrict__ bias,
                                                    float* __restrict__ out) {
  __shared__ u16 Asm[2][128 * 64];
  __shared__ u16 Bsm[2][128 * 64];
  const int tid = threadIdx.x, lane = tid & 63, w = tid >> 6;
  const int quad = lane >> 4, l15 = lane & 15;
  const int m0 = (blockIdx.x & 63) * 128, n0 = (blockIdx.x >> 6) * 128;
  const int wm = (w >> 1) * 64, wn = (w & 1) * 64;
  const int srow = lane >> 3;
  const int gcc = ((lane & 7) ^ srow) * 8;
  const int rx8 = (l15 & 7);
  f32x4 acc[4][4];
  #pragma unroll
  for (int i = 0; i < 4; i++)
    #pragma unroll
    for (int j = 0; j < 4; j++)
      #pragma unroll
      for (int r = 0; r < 4; r++) acc[i][j][r] = 0.f;

#define STAGEP(pb_, kt_) {                                                             \
    _Pragma("unroll") for (int c = 0; c < 4; ++c) {                                    \
      int chunk = w * 4 + c;                                                           \
      int row = chunk * 8 + srow;                                                      \
      glds16(&Asm[pb_][chunk * 512], &A[(size_t)(m0 + row) * 1024 + (kt_) + gcc]);     \
      glds16(&Bsm[pb_][chunk * 512], &Bt[(size_t)(n0 + row) * 1024 + (kt_) + gcc]);    \
    }                                                                                  \
  }

  STAGEP(0, 0)
  __syncthreads();
  for (int kt = 0, t = 0; kt < 1024; kt += 64, ++t) {
    const int pb = t & 1;
    if (kt + 64 < 1024) STAGEP(pb ^ 1, kt + 64)
    #pragma unroll
    for (int ks = 0; ks < 2; ++ks) {
      int pc = ((ks * 4 + quad) ^ rx8) * 8;
      short8 av[4], bv[4];
      #pragma unroll
      for (int i = 0; i < 4; i++)
        av[i] = *(const short8*)&Asm[pb][(wm + i * 16 + l15) * 64 + pc];
      #pragma unroll
      for (int j = 0; j < 4; j++)
        bv[j] = *(const short8*)&Bsm[pb][(wn + j * 16 + l15) * 64 + pc];
      #pragma unroll
      for (int i = 0; i < 4; i++)
        #pragma unroll
        for (int j = 0; j < 4; j++)
          acc[i][j] = MFMA(av[i], bv[j], acc[i][j]);
    }
    __syncthreads();
  }
#undef STAGEP

  #pragma unroll
  for (int j = 0; j < 4; j++) {
    int col = n0 + wn + j * 16 + l15;
    float bj = bias[col];
    #pragma unroll
    for (int i = 0; i < 4; i++) {
      #pragma unroll
      for (int r = 0; r < 4; r++) {
        int row = m0 + wm + i * 16 + quad * 4 + r;
        out[(size_t)row * 1024 + col] = acc[i][j][r] + bj;
      }
    }
  }
}

// ---------- launch ----------
extern "C" void kernel_launch(void* const* d_in, const int* in_sizes, int n_in,
                              void* d_out, int out_size, void* d_ws, size_t ws_size,
                              hipStream_t stream) {
  (void)in_sizes; (void)n_in; (void)out_size; (void)ws_size;
  const float* x     = (const float*)d_in[0];
  const int*   mask  = (const int*)d_in[1];
  const float* Wqkv  = (const float*)d_in[2];
  const float* Wproj = (const float*)d_in[3];
  const float* bproj = (const float*)d_in[4];
  float* out = (float*)d_out;
  char* ws = (char*)d_ws;

  size_t off = 0;
  u16* xb     = (u16*)(ws + off); off += 8192ull * 1024 * 2;   // x bf16; REUSED as aobuf
  u16* wqkvt  = (u16*)(ws + off); off += 3072ull * 1024 * 2;   // Wqkv^T bf16 [3072][1024]
  u16* wprojt = (u16*)(ws + off); off += 1024ull * 1024 * 2;   // Wproj^T bf16 [1024][1024]
  u16* qbuf   = (u16*)(ws + off); off += 8192ull * 1024 * 2;   // Q (pre-scaled) bf16
  u16* kcbuf  = (u16*)(ws + off); off += 4096ull * 2048 * 2;   // K compact [b][slot][1024]
  u16* vtcbuf = (u16*)(ws + off); off += 4096ull * 2048 * 2;   // V^T compact [b][d][slot]
  int* s2t    = (int*)(ws + off); off += 8192ull * 4;          // slot -> global token
  int* nkbuf  = (int*)(ws + off); off += 4 * 4;                // per-batch nk
  u16* aobuf  = xb;   // xb's last read is gemm_fused; attn writes ao after -> safe alias

  prep<<<9220, 256, 0, stream>>>(x, mask, Wqkv, Wproj, xb, wqkvt, wprojt, s2t, nkbuf);
  gemm_fused<<<1536, 256, 0, stream>>>(xb, wqkvt, s2t, nkbuf, qbuf, kcbuf, vtcbuf);
  attn_kernel<<<dim3(16, 4, 8), 256, 0, stream>>>(qbuf, kcbuf, vtcbuf, nkbuf, aobuf);
  gemm_proj<<<512, 256, 0, stream>>>(aobuf, wprojt, bproj, out);
}